// Round 12
// baseline (82.636 us; speedup 1.0000x reference)
//
#include <hip/hip_runtime.h>
#include <hip/hip_bf16.h>

typedef __attribute__((ext_vector_type(8))) short bf16x8;
typedef __attribute__((ext_vector_type(4))) float f32x4;
typedef __hip_bfloat16 bf16;

#define NROWS 8192
#define DIN   2048
#define DD    768
#define CCLS  100

// ---------------- fused prep kernel (R11-verified) ----------------
__global__ __launch_bounds__(256) void k_prep(const float* __restrict__ x,
                                              const float* __restrict__ W,
                                              const float* __restrict__ mu,
                                              const float* __restrict__ P,
                                              bf16* __restrict__ xb,
                                              bf16* __restrict__ Wt,
                                              bf16* __restrict__ BT,
                                              float* __restrict__ hmPart) {
  __shared__ float muL[DD];
  __shared__ float partial[4][64];
  __shared__ float tile[32][33];
  const int b = blockIdx.x;
  const int tid = threadIdx.x;

  if (b < 1200) {                     // ---- prep_mu ----
    const int c = b / 12, ch = b % 12;
    for (int i = tid; i < DD; i += 256) muL[i] = mu[(long)c * DD + i];
    __syncthreads();
    const int colL = tid & 63, dgrp = tid >> 6;
    const float* Pc = P + ch * 64 + colL;
    float acc = 0.f;
    const int dbase = dgrp * 192;
#pragma unroll 1
    for (int d0 = dbase; d0 < dbase + 192; d0 += 16) {
      float pv[16];
#pragma unroll
      for (int u = 0; u < 16; ++u) pv[u] = Pc[(long)(d0 + u) * DD];
#pragma unroll
      for (int u = 0; u < 16; ++u) acc += pv[u] * muL[d0 + u];
    }
    partial[dgrp][colL] = acc;
    __syncthreads();
    if (tid < 64) {
      const int col = ch * 64 + tid;
      float s = partial[0][tid] + partial[1][tid] + partial[2][tid] + partial[3][tid];
      BT[(long)(DD + c) * DD + col] = __float2bfloat16(s);
      float hv = s * muL[col];
      hv += __shfl_xor(hv, 1, 64);
      hv += __shfl_xor(hv, 2, 64);
      hv += __shfl_xor(hv, 4, 64);
      hv += __shfl_xor(hv, 8, 64);
      hv += __shfl_xor(hv, 16, 64);
      hv += __shfl_xor(hv, 32, 64);
      if (tid == 0) hmPart[ch * 128 + c] = hv;
    }
  } else if (b < 2736) {              // ---- transpose_W ----
    const int t = b - 1200;
    const int tx = tid & 31, ty = tid >> 5;
    const int n0 = (t % 24) * 32, k0 = (t / 24) * 32;
#pragma unroll
    for (int i = 0; i < 4; ++i)
      tile[ty + 8*i][tx] = W[(long)(k0 + ty + 8*i) * DD + n0 + tx];
    __syncthreads();
#pragma unroll
    for (int i = 0; i < 4; ++i)
      Wt[(long)(n0 + ty + 8*i) * DIN + k0 + tx] = __float2bfloat16(tile[tx][ty + 8*i]);
  } else if (b < 5424) {              // ---- convert_P ----
    const int id = (b - 2736) * 256 + tid;
    const int r = id / DD;
    if (r < DD)                BT[id] = __float2bfloat16(P[id]);
    else if (r >= DD + CCLS)   BT[id] = __float2bfloat16(0.f);
  } else {                            // ---- convert_x ----
    const long i = ((long)(b - 5424) * 256 + tid) * 8;
    float4 v0 = *(const float4*)(x + i);
    float4 v1 = *(const float4*)(x + i + 4);
    union { bf16 h[8]; bf16x8 v; } tcv;
    tcv.h[0] = __float2bfloat16(v0.x); tcv.h[1] = __float2bfloat16(v0.y);
    tcv.h[2] = __float2bfloat16(v0.z); tcv.h[3] = __float2bfloat16(v0.w);
    tcv.h[4] = __float2bfloat16(v1.x); tcv.h[5] = __float2bfloat16(v1.y);
    tcv.h[6] = __float2bfloat16(v1.z); tcv.h[7] = __float2bfloat16(v1.w);
    *(bf16x8*)(xb + i) = tcv.v;
  }
}

// ---------------- GEMM core (128x128, BK=64, 4 waves, T1+T2) ----------------
// R12: T4 counted-vmcnt pipeline. Raw s_barrier + "s_waitcnt vmcnt(8)" replaces
// __syncthreads' vmcnt(0) drain. Prologue stages tiles t0,t1 (16 loads in flight);
// step t waits ONLY for its own tile's 8 loads (the oldest 8 — vmcnt waits oldest,
// m135), computes, barriers, then re-stages its buffer for tile t+2. Loads get
// ~2 COMPUTE phases of latency cover and barriers never wait on the newest stage.
// Race audit: barrier #2 between COMPUTE(buf) and STAGE(buf,t+2) -> no wave
// overwrites a buffer any wave still reads; per-wave vmcnt BEFORE barrier #1 ->
// after barrier all waves' tile-t loads are in LDS. "memory" clobbers fence the
// C++ LDS reads across the raw barriers.

#define STAGE(As_, Bs_, kt_)                                                            \
  do {                                                                                  \
    _Pragma("unroll")                                                                   \
    for (int i = 0; i < 4; ++i) {                                                       \
      const int rr = i * 32 + w * 8;                                                    \
      const bf16* gA = A + (rowA0 + rr + sr) * (long)LDK + (kt_) + sc;                  \
      const bf16* gB = B + (rowB0 + rr + sr) * (long)LDK + (kt_) + sc;                  \
      __builtin_amdgcn_global_load_lds(                                                 \
          (const __attribute__((address_space(1))) unsigned int*)gA,                    \
          (__attribute__((address_space(3))) unsigned int*)((As_) + rr * 64), 16, 0, 0);\
      __builtin_amdgcn_global_load_lds(                                                 \
          (const __attribute__((address_space(1))) unsigned int*)gB,                    \
          (__attribute__((address_space(3))) unsigned int*)((Bs_) + rr * 64), 16, 0, 0);\
    }                                                                                   \
  } while (0)

#define COMPUTE(As_, Bs_)                                                               \
  do {                                                                                  \
    _Pragma("unroll")                                                                   \
    for (int kk = 0; kk < 64; kk += 32) {                                               \
      const int slot = (fq ^ (kk >> 3) ^ (fr & 7)) * 8;  /* T2 swizzled 16B slot */     \
      bf16x8 av[4], bv[4];                                                              \
      _Pragma("unroll")                                                                 \
      for (int m = 0; m < 4; ++m)                                                       \
        av[m] = *(const bf16x8*)((As_) + (wr * 64 + m * 16 + fr) * 64 + slot);          \
      _Pragma("unroll")                                                                 \
      for (int n = 0; n < 4; ++n)                                                       \
        bv[n] = *(const bf16x8*)((Bs_) + (wc * 64 + n * 16 + fr) * 64 + slot);          \
      _Pragma("unroll")                                                                 \
      for (int m = 0; m < 4; ++m)                                                       \
        _Pragma("unroll")                                                               \
        for (int n = 0; n < 4; ++n)                                                     \
          acc[m][n] = __builtin_amdgcn_mfma_f32_16x16x32_bf16(av[m], bv[n],             \
                                                              acc[m][n], 0, 0, 0);      \
    }                                                                                   \
  } while (0)

// counted-vmcnt step: wait own tile (oldest 8; 0 at the tail), barrier, compute,
// barrier, re-stage this buffer for tile t+2 (if it exists).
#define PIPE_STEP(As_, Bs_, kt_)                                                        \
  do {                                                                                  \
    if ((kt_) + 64 < LDK) asm volatile("s_waitcnt vmcnt(8)" ::: "memory");              \
    else                  asm volatile("s_waitcnt vmcnt(0)" ::: "memory");              \
    __builtin_amdgcn_s_barrier();                                                       \
    asm volatile("" ::: "memory");                                                      \
    COMPUTE(As_, Bs_);                                                                  \
    asm volatile("" ::: "memory");                                                      \
    __builtin_amdgcn_s_barrier();                                                       \
    if ((kt_) + 128 < LDK) STAGE(As_, Bs_, (kt_) + 128);                                \
  } while (0)

template<int LDK>
__device__ __forceinline__ void gemm_mainloop_pf(
    const bf16* __restrict__ A, const bf16* __restrict__ B,
    long rowA0, long rowB0,
    bf16* As0, bf16* Bs0, bf16* As1, bf16* Bs1, f32x4 acc[4][4])
{
  const int tid  = threadIdx.x;
  const int lane = tid & 63;
  const int w    = tid >> 6;            // 0..3
  const int wr = w >> 1, wc = w & 1;
  const int fr = lane & 15, fq = lane >> 4;
  const int sr = lane >> 3;                      // staging row within 8-row chunk (0..7)
  const int sc = (((lane & 7) ^ sr) * 8);        // T2 inverse-swizzled global 16B slot

  STAGE(As0, Bs0, 0);
  STAGE(As1, Bs1, 64);                           // LDK >= 128 always here
  // LDK/64 even (32 and 12): statically 2-step unrolled, no pointer swap.
#pragma unroll 1
  for (int kt = 0; kt < LDK; kt += 128) {
    PIPE_STEP(As0, Bs0, kt);                     // tile kt/64   (stages tile +2)
    PIPE_STEP(As1, Bs1, kt + 64);                // tile kt/64+1 (stages tile +3)
  }
}

// GEMM1: zb = xb @ Wt^T   [8192,2048]x[768,2048]^T -> bf16 [8192,768]
// flat grid 384, XCD swizzle: each XCD owns 48 blocks = 8 bm-panels x 6 bn.
__global__ __launch_bounds__(256, 2) void k_gemm1(const bf16* __restrict__ xb,
                                                  const bf16* __restrict__ Wt,
                                                  bf16* __restrict__ zb) {
  __shared__ __align__(16) bf16 As0[128 * 64], Bs0[128 * 64];
  __shared__ __align__(16) bf16 As1[128 * 64], Bs1[128 * 64];
  f32x4 acc[4][4];
#pragma unroll
  for (int m = 0; m < 4; ++m)
#pragma unroll
    for (int n = 0; n < 4; ++n) acc[m][n] = (f32x4){0.f, 0.f, 0.f, 0.f};
  const int bid = blockIdx.x;                 // 0..383
  const int s = (bid & 7) * 48 + (bid >> 3);  // bijective: 384 % 8 == 0
  const long bm = s / 6, bn = s % 6;
  gemm_mainloop_pf<DIN>(xb, Wt, bm * 128, bn * 128, As0, Bs0, As1, Bs1, acc);
  const int tid = threadIdx.x, lane = tid & 63, w = tid >> 6;
  const int wr = w >> 1, wc = w & 1, fr = lane & 15, fq = lane >> 4;
#pragma unroll
  for (int m = 0; m < 4; ++m)
#pragma unroll
    for (int n = 0; n < 4; ++n)
#pragma unroll
      for (int j = 0; j < 4; ++j) {
        long row = bm * 128 + wr * 64 + m * 16 + fq * 4 + j;
        long col = bn * 128 + wc * 64 + n * 16 + fr;
        zb[row * DD + col] = __float2bfloat16(acc[m][n][j]);
      }
}

// GEMM2: out2 = zb @ BT^T, BT = [P | muP | 0] as [896,768].
// flat grid 448, XCD swizzle: each XCD owns 56 blocks = 8 bm-panels x 7 bn.
// bn<6: zP tile -> rowdot with zb -> STORE to zPzPart[(bn*2+wc)][row]
//   (part key includes wc — waves (wr,0)/(wr,1) hold different 64-col halves.)
// bn==6: score tile -> max_c(s - hm[c]) -> smax[row]; hm summed from hmPart,
//   c>=100 -> +1e30 (pad classes).
__global__ __launch_bounds__(256, 2) void k_gemm2(const bf16* __restrict__ zb,
                                                  const bf16* __restrict__ BT,
                                                  const float* __restrict__ hmPart,
                                                  float* __restrict__ zPzPart,
                                                  float* __restrict__ smax) {
  __shared__ __align__(16) bf16 As0[128 * 64], Bs0[128 * 64];
  __shared__ __align__(16) bf16 As1[128 * 64], Bs1[128 * 64];
  __shared__ float sred[2][128];
  f32x4 acc[4][4];
#pragma unroll
  for (int m = 0; m < 4; ++m)
#pragma unroll
    for (int n = 0; n < 4; ++n) acc[m][n] = (f32x4){0.f, 0.f, 0.f, 0.f};
  const int bid = blockIdx.x;                 // 0..447
  const int s = (bid & 7) * 56 + (bid >> 3);  // bijective: 448 % 8 == 0
  const long bm = s / 7, bn = s % 7;
  gemm_mainloop_pf<DD>(zb, BT, bm * 128, bn * 128, As0, Bs0, As1, Bs1, acc);
  const int tid = threadIdx.x, lane = tid & 63, w = tid >> 6;
  const int wr = w >> 1, wc = w & 1, fr = lane & 15, fq = lane >> 4;

  if (bn < 6) {
    float p[4][4];
#pragma unroll
    for (int m = 0; m < 4; ++m)
#pragma unroll
      for (int j = 0; j < 4; ++j) p[m][j] = 0.f;
#pragma unroll
    for (int m = 0; m < 4; ++m)
#pragma unroll
      for (int n = 0; n < 4; ++n)
#pragma unroll
        for (int j = 0; j < 4; ++j) {
          long row = bm * 128 + wr * 64 + m * 16 + fq * 4 + j;
          long col = bn * 128 + wc * 64 + n * 16 + fr;
          p[m][j] += acc[m][n][j] * __bfloat162float(zb[row * DD + col]);
        }
#pragma unroll
    for (int m = 0; m < 4; ++m)
#pragma unroll
      for (int j = 0; j < 4; ++j) {
        float v = p[m][j];
        v += __shfl_xor(v, 1, 64);
        v += __shfl_xor(v, 2, 64);
        v += __shfl_xor(v, 4, 64);
        v += __shfl_xor(v, 8, 64);
        if (fr == 0)
          zPzPart[(bn * 2 + wc) * NROWS + bm * 128 + wr * 64 + m * 16 + fq * 4 + j] = v;
      }
  } else {
    float hmv[4];
#pragma unroll
    for (int n = 0; n < 4; ++n) {
      const int c = wc * 64 + n * 16 + fr;
      if (c < CCLS) {
        float t = 0.f;
#pragma unroll
        for (int j = 0; j < 12; ++j) t += hmPart[j * 128 + c];
        hmv[n] = 0.5f * t;
      } else {
        hmv[n] = 1e30f;
      }
    }
    float mx[4][4];
#pragma unroll
    for (int m = 0; m < 4; ++m)
#pragma unroll
      for (int j = 0; j < 4; ++j) mx[m][j] = -3e38f;
#pragma unroll
    for (int m = 0; m < 4; ++m)
#pragma unroll
      for (int n = 0; n < 4; ++n)
#pragma unroll
        for (int j = 0; j < 4; ++j)
          mx[m][j] = fmaxf(mx[m][j], acc[m][n][j] - hmv[n]);
#pragma unroll
    for (int m = 0; m < 4; ++m)
#pragma unroll
      for (int j = 0; j < 4; ++j) {
        float v = mx[m][j];
        v = fmaxf(v, __shfl_xor(v, 1, 64));
        v = fmaxf(v, __shfl_xor(v, 2, 64));
        v = fmaxf(v, __shfl_xor(v, 4, 64));
        v = fmaxf(v, __shfl_xor(v, 8, 64));
        if (fr == 0) sred[wc][wr * 64 + m * 16 + fq * 4 + j] = v;
      }
    __syncthreads();
    if (tid < 128) smax[bm * 128 + tid] = fmaxf(sred[0][tid], sred[1][tid]);
  }
}

__global__ void k_final(const float* __restrict__ smax, const float* __restrict__ zPzPart,
                        float* __restrict__ out) {
  int i = blockIdx.x * 256 + threadIdx.x;
  if (i < NROWS) {
    float t = 0.f;
#pragma unroll
    for (int b = 0; b < 12; ++b) t += zPzPart[b * NROWS + i];
    out[i] = smax[i] - 0.5f * t;
  }
}

// ---------------- launch ----------------

extern "C" void kernel_launch(void* const* d_in, const int* in_sizes, int n_in,
                              void* d_out, int out_size, void* d_ws, size_t ws_size,
                              hipStream_t stream) {
  const float* x  = (const float*)d_in[0];
  const float* W  = (const float*)d_in[1];
  const float* mu = (const float*)d_in[2];
  const float* P  = (const float*)d_in[3];
  float* out = (float*)d_out;

  char* ws = (char*)d_ws;
  bf16*  xb      = (bf16*)(ws);                    // 33,554,432
  bf16*  Wt      = (bf16*)(ws + 33554432);         //  3,145,728
  bf16*  BT      = (bf16*)(ws + 36700160);         //  1,376,256
  bf16*  zb      = (bf16*)(ws + 38076416);         // 12,582,912
  float* hmPart  = (float*)(ws + 50659328);        // 12*128*4 = 6,144 B
  float* smax    = (float*)(ws + 50665472);        // 32,768 B
  float* zPzPart = (float*)(ws + 50698240);        // 12*8192*4 = 393,216 B (end 51,091,456)

  k_prep  <<<13616, 256, 0, stream>>>(x, W, mu, P, xb, Wt, BT, hmPart);
  k_gemm1 <<<384, 256, 0, stream>>>(xb, Wt, zb);
  k_gemm2 <<<448, 256, 0, stream>>>(zb, BT, hmPart, zPzPart, smax);
  k_final <<<32, 256, 0, stream>>>(smax, zPzPart, out);
}

// Round 13
// 79.573 us; speedup vs baseline: 1.0385x; 1.0385x over previous
//
#include <hip/hip_runtime.h>
#include <hip/hip_bf16.h>

typedef __attribute__((ext_vector_type(8))) short bf16x8;
typedef __attribute__((ext_vector_type(4))) float f32x4;
typedef __hip_bfloat16 bf16;

#define NROWS 8192
#define DIN   2048
#define DD    768
#define CCLS  100

// ---------------- fused prep kernel (R11-verified) ----------------
__global__ __launch_bounds__(256) void k_prep(const float* __restrict__ x,
                                              const float* __restrict__ W,
                                              const float* __restrict__ mu,
                                              const float* __restrict__ P,
                                              bf16* __restrict__ xb,
                                              bf16* __restrict__ Wt,
                                              bf16* __restrict__ BT,
                                              float* __restrict__ hmPart) {
  __shared__ float muL[DD];
  __shared__ float partial[4][64];
  __shared__ float tile[32][33];
  const int b = blockIdx.x;
  const int tid = threadIdx.x;

  if (b < 1200) {                     // ---- prep_mu ----
    const int c = b / 12, ch = b % 12;
    for (int i = tid; i < DD; i += 256) muL[i] = mu[(long)c * DD + i];
    __syncthreads();
    const int colL = tid & 63, dgrp = tid >> 6;
    const float* Pc = P + ch * 64 + colL;
    float acc = 0.f;
    const int dbase = dgrp * 192;
#pragma unroll 1
    for (int d0 = dbase; d0 < dbase + 192; d0 += 16) {
      float pv[16];
#pragma unroll
      for (int u = 0; u < 16; ++u) pv[u] = Pc[(long)(d0 + u) * DD];
#pragma unroll
      for (int u = 0; u < 16; ++u) acc += pv[u] * muL[d0 + u];
    }
    partial[dgrp][colL] = acc;
    __syncthreads();
    if (tid < 64) {
      const int col = ch * 64 + tid;
      float s = partial[0][tid] + partial[1][tid] + partial[2][tid] + partial[3][tid];
      BT[(long)(DD + c) * DD + col] = __float2bfloat16(s);
      float hv = s * muL[col];
      hv += __shfl_xor(hv, 1, 64);
      hv += __shfl_xor(hv, 2, 64);
      hv += __shfl_xor(hv, 4, 64);
      hv += __shfl_xor(hv, 8, 64);
      hv += __shfl_xor(hv, 16, 64);
      hv += __shfl_xor(hv, 32, 64);
      if (tid == 0) hmPart[ch * 128 + c] = hv;
    }
  } else if (b < 2736) {              // ---- transpose_W ----
    const int t = b - 1200;
    const int tx = tid & 31, ty = tid >> 5;
    const int n0 = (t % 24) * 32, k0 = (t / 24) * 32;
#pragma unroll
    for (int i = 0; i < 4; ++i)
      tile[ty + 8*i][tx] = W[(long)(k0 + ty + 8*i) * DD + n0 + tx];
    __syncthreads();
#pragma unroll
    for (int i = 0; i < 4; ++i)
      Wt[(long)(n0 + ty + 8*i) * DIN + k0 + tx] = __float2bfloat16(tile[tx][ty + 8*i]);
  } else if (b < 5424) {              // ---- convert_P ----
    const int id = (b - 2736) * 256 + tid;
    const int r = id / DD;
    if (r < DD)                BT[id] = __float2bfloat16(P[id]);
    else if (r >= DD + CCLS)   BT[id] = __float2bfloat16(0.f);
  } else {                            // ---- convert_x ----
    const long i = ((long)(b - 5424) * 256 + tid) * 8;
    float4 v0 = *(const float4*)(x + i);
    float4 v1 = *(const float4*)(x + i + 4);
    union { bf16 h[8]; bf16x8 v; } tcv;
    tcv.h[0] = __float2bfloat16(v0.x); tcv.h[1] = __float2bfloat16(v0.y);
    tcv.h[2] = __float2bfloat16(v0.z); tcv.h[3] = __float2bfloat16(v0.w);
    tcv.h[4] = __float2bfloat16(v1.x); tcv.h[5] = __float2bfloat16(v1.y);
    tcv.h[6] = __float2bfloat16(v1.z); tcv.h[7] = __float2bfloat16(v1.w);
    *(bf16x8*)(xb + i) = tcv.v;
  }
}

// ---------------- GEMM core (templated: BM=128, BN=16*NBF*2, BK=64, 4 waves) --------
// R13: back to the R11-verified __syncthreads 2-phase loop (R12's counted-vmcnt was
// null — 2-phase is not drain-bound here). Template params let gemm1 use BN=96
// (NBF=3, NCHB=12) for exact 2-blocks/CU slot packing (512 blocks), gemm2 keeps
// BN=128 (NBF=4, NCHB=16). T1 XCD swizzle + T2 XOR bank-swizzle invariant:
//   LDS[row][s'] = G[row][s' ^ (row&7)]; reads use slot' = fq ^ (kk>>3) ^ (fr&7)
//   (all fragment-row bases are multiples of 8 -> row&7 == fr&7).

template<int LDK, int NBF, int NCHB>
__device__ __forceinline__ void gemm_mainloop(
    const bf16* __restrict__ A, const bf16* __restrict__ B,
    long rowA0, long rowB0,
    bf16* As0, bf16* Bs0, bf16* As1, bf16* Bs1, f32x4 acc[4][NBF])
{
  const int tid  = threadIdx.x;
  const int lane = tid & 63;
  const int w    = tid >> 6;            // 0..3
  const int wr = w >> 1, wc = w & 1;
  const int fr = lane & 15, fq = lane >> 4;
  const int sr = lane >> 3;                      // staging row within 8-row chunk
  const int sc = (((lane & 7) ^ sr) * 8);        // T2 inverse-swizzled global 16B slot
  constexpr int NCH = 16 + NCHB;                 // 16 A-chunks + NCHB B-chunks
  constexpr int NPW = NCH / 4;                   // chunks per wave

  auto stage = [&](bf16* As, bf16* Bs, int kt) {
#pragma unroll
    for (int i = 0; i < NPW; ++i) {
      const int c = w * NPW + i;                 // wave-uniform chunk id
      if (c < 16) {                              // A chunk: rows c*8..c*8+8
        const bf16* g = A + (rowA0 + c * 8 + sr) * (long)LDK + kt + sc;
        __builtin_amdgcn_global_load_lds(
            (const __attribute__((address_space(1))) unsigned int*)g,
            (__attribute__((address_space(3))) unsigned int*)(As + c * 512), 16, 0, 0);
      } else {                                   // B chunk
        const int cb = c - 16;
        const bf16* g = B + (rowB0 + cb * 8 + sr) * (long)LDK + kt + sc;
        __builtin_amdgcn_global_load_lds(
            (const __attribute__((address_space(1))) unsigned int*)g,
            (__attribute__((address_space(3))) unsigned int*)(Bs + cb * 512), 16, 0, 0);
      }
    }
  };
  auto compute = [&](const bf16* As, const bf16* Bs) {
#pragma unroll
    for (int kk = 0; kk < 64; kk += 32) {
      const int slot = (fq ^ (kk >> 3) ^ (fr & 7)) * 8;
      bf16x8 av[4], bv[NBF];
#pragma unroll
      for (int m = 0; m < 4; ++m)
        av[m] = *(const bf16x8*)(As + (wr * 64 + m * 16 + fr) * 64 + slot);
#pragma unroll
      for (int n = 0; n < NBF; ++n)
        bv[n] = *(const bf16x8*)(Bs + (wc * (NBF * 16) + n * 16 + fr) * 64 + slot);
#pragma unroll
      for (int m = 0; m < 4; ++m)
#pragma unroll
        for (int n = 0; n < NBF; ++n)
          acc[m][n] = __builtin_amdgcn_mfma_f32_16x16x32_bf16(av[m], bv[n],
                                                              acc[m][n], 0, 0, 0);
    }
  };

  stage(As0, Bs0, 0);
  // LDK/64 even (32 and 12): statically 2x-unrolled double buffer, no pointer swap.
#pragma unroll 1
  for (int kt = 0; kt < LDK; kt += 128) {
    __syncthreads();                          // buf0 staged + all waves synced
    if (kt + 64 < LDK) stage(As1, Bs1, kt + 64);
    compute(As0, Bs0);
    __syncthreads();                          // buf1 staged + reads of buf0 done
    if (kt + 128 < LDK) stage(As0, Bs0, kt + 128);
    compute(As1, Bs1);
  }
}

// GEMM1: zb = xb @ Wt^T   [8192,2048]x[768,2048]^T -> bf16 [8192,768]
// R13: BN=96 -> flat grid 512 = EXACTLY the 2-blocks/CU slot capacity (was 384/512
// slots = 25% tail idle). acc[4][3], LDS 56KB (2 blocks/CU). XCD swizzle: 512%8==0.
__global__ __launch_bounds__(256, 2) void k_gemm1(const bf16* __restrict__ xb,
                                                  const bf16* __restrict__ Wt,
                                                  bf16* __restrict__ zb) {
  __shared__ __align__(16) bf16 As0[128 * 64], Bs0[96 * 64];
  __shared__ __align__(16) bf16 As1[128 * 64], Bs1[96 * 64];
  f32x4 acc[4][3];
#pragma unroll
  for (int m = 0; m < 4; ++m)
#pragma unroll
    for (int n = 0; n < 3; ++n) acc[m][n] = (f32x4){0.f, 0.f, 0.f, 0.f};
  const int bid = blockIdx.x;                 // 0..511
  const int s = (bid & 7) * 64 + (bid >> 3);  // bijective: 512 % 8 == 0
  const long bm = s / 8, bn = s % 8;          // 64 bm-panels x 8 bn-tiles of 96
  gemm_mainloop<DIN, 3, 12>(xb, Wt, bm * 128, bn * 96, As0, Bs0, As1, Bs1, acc);
  const int tid = threadIdx.x, lane = tid & 63, w = tid >> 6;
  const int wr = w >> 1, wc = w & 1, fr = lane & 15, fq = lane >> 4;
#pragma unroll
  for (int m = 0; m < 4; ++m)
#pragma unroll
    for (int n = 0; n < 3; ++n)
#pragma unroll
      for (int j = 0; j < 4; ++j) {
        long row = bm * 128 + wr * 64 + m * 16 + fq * 4 + j;
        long col = bn * 96 + wc * 48 + n * 16 + fr;
        zb[row * DD + col] = __float2bfloat16(acc[m][n][j]);
      }
}

// GEMM2: out2 = zb @ BT^T, BT = [P | muP | 0] as [896,768].  (R11-verified)
// flat grid 448, XCD swizzle.
// bn<6: zP tile -> rowdot with zb -> STORE to zPzPart[(bn*2+wc)][row]
//   (part key includes wc — waves (wr,0)/(wr,1) hold different 64-col halves.)
// bn==6: score tile -> max_c(s - hm[c]) -> smax[row]; hm summed from hmPart,
//   c>=100 -> +1e30 (pad classes).
__global__ __launch_bounds__(256, 2) void k_gemm2(const bf16* __restrict__ zb,
                                                  const bf16* __restrict__ BT,
                                                  const float* __restrict__ hmPart,
                                                  float* __restrict__ zPzPart,
                                                  float* __restrict__ smax) {
  __shared__ __align__(16) bf16 As0[128 * 64], Bs0[128 * 64];
  __shared__ __align__(16) bf16 As1[128 * 64], Bs1[128 * 64];
  __shared__ float sred[2][128];
  f32x4 acc[4][4];
#pragma unroll
  for (int m = 0; m < 4; ++m)
#pragma unroll
    for (int n = 0; n < 4; ++n) acc[m][n] = (f32x4){0.f, 0.f, 0.f, 0.f};
  const int bid = blockIdx.x;                 // 0..447
  const int s = (bid & 7) * 56 + (bid >> 3);  // bijective: 448 % 8 == 0
  const long bm = s / 7, bn = s % 7;
  gemm_mainloop<DD, 4, 16>(zb, BT, bm * 128, bn * 128, As0, Bs0, As1, Bs1, acc);
  const int tid = threadIdx.x, lane = tid & 63, w = tid >> 6;
  const int wr = w >> 1, wc = w & 1, fr = lane & 15, fq = lane >> 4;

  if (bn < 6) {
    float p[4][4];
#pragma unroll
    for (int m = 0; m < 4; ++m)
#pragma unroll
      for (int j = 0; j < 4; ++j) p[m][j] = 0.f;
#pragma unroll
    for (int m = 0; m < 4; ++m)
#pragma unroll
      for (int n = 0; n < 4; ++n)
#pragma unroll
        for (int j = 0; j < 4; ++j) {
          long row = bm * 128 + wr * 64 + m * 16 + fq * 4 + j;
          long col = bn * 128 + wc * 64 + n * 16 + fr;
          p[m][j] += acc[m][n][j] * __bfloat162float(zb[row * DD + col]);
        }
#pragma unroll
    for (int m = 0; m < 4; ++m)
#pragma unroll
      for (int j = 0; j < 4; ++j) {
        float v = p[m][j];
        v += __shfl_xor(v, 1, 64);
        v += __shfl_xor(v, 2, 64);
        v += __shfl_xor(v, 4, 64);
        v += __shfl_xor(v, 8, 64);
        if (fr == 0)
          zPzPart[(bn * 2 + wc) * NROWS + bm * 128 + wr * 64 + m * 16 + fq * 4 + j] = v;
      }
  } else {
    float hmv[4];
#pragma unroll
    for (int n = 0; n < 4; ++n) {
      const int c = wc * 64 + n * 16 + fr;
      if (c < CCLS) {
        float t = 0.f;
#pragma unroll
        for (int j = 0; j < 12; ++j) t += hmPart[j * 128 + c];
        hmv[n] = 0.5f * t;
      } else {
        hmv[n] = 1e30f;
      }
    }
    float mx[4][4];
#pragma unroll
    for (int m = 0; m < 4; ++m)
#pragma unroll
      for (int j = 0; j < 4; ++j) mx[m][j] = -3e38f;
#pragma unroll
    for (int m = 0; m < 4; ++m)
#pragma unroll
      for (int n = 0; n < 4; ++n)
#pragma unroll
        for (int j = 0; j < 4; ++j)
          mx[m][j] = fmaxf(mx[m][j], acc[m][n][j] - hmv[n]);
#pragma unroll
    for (int m = 0; m < 4; ++m)
#pragma unroll
      for (int j = 0; j < 4; ++j) {
        float v = mx[m][j];
        v = fmaxf(v, __shfl_xor(v, 1, 64));
        v = fmaxf(v, __shfl_xor(v, 2, 64));
        v = fmaxf(v, __shfl_xor(v, 4, 64));
        v = fmaxf(v, __shfl_xor(v, 8, 64));
        if (fr == 0) sred[wc][wr * 64 + m * 16 + fq * 4 + j] = v;
      }
    __syncthreads();
    if (tid < 128) smax[bm * 128 + tid] = fmaxf(sred[0][tid], sred[1][tid]);
  }
}

__global__ void k_final(const float* __restrict__ smax, const float* __restrict__ zPzPart,
                        float* __restrict__ out) {
  int i = blockIdx.x * 256 + threadIdx.x;
  if (i < NROWS) {
    float t = 0.f;
#pragma unroll
    for (int b = 0; b < 12; ++b) t += zPzPart[b * NROWS + i];
    out[i] = smax[i] - 0.5f * t;
  }
}

// ---------------- launch ----------------

extern "C" void kernel_launch(void* const* d_in, const int* in_sizes, int n_in,
                              void* d_out, int out_size, void* d_ws, size_t ws_size,
                              hipStream_t stream) {
  const float* x  = (const float*)d_in[0];
  const float* W  = (const float*)d_in[1];
  const float* mu = (const float*)d_in[2];
  const float* P  = (const float*)d_in[3];
  float* out = (float*)d_out;

  char* ws = (char*)d_ws;
  bf16*  xb      = (bf16*)(ws);                    // 33,554,432
  bf16*  Wt      = (bf16*)(ws + 33554432);         //  3,145,728
  bf16*  BT      = (bf16*)(ws + 36700160);         //  1,376,256
  bf16*  zb      = (bf16*)(ws + 38076416);         // 12,582,912
  float* hmPart  = (float*)(ws + 50659328);        // 12*128*4 = 6,144 B
  float* smax    = (float*)(ws + 50665472);        // 32,768 B
  float* zPzPart = (float*)(ws + 50698240);        // 12*8192*4 = 393,216 B (end 51,091,456)

  k_prep  <<<13616, 256, 0, stream>>>(x, W, mu, P, xb, Wt, BT, hmPart);
  k_gemm1 <<<512, 256, 0, stream>>>(xb, Wt, zb);
  k_gemm2 <<<448, 256, 0, stream>>>(zb, BT, hmPart, zPzPart, smax);
  k_final <<<32, 256, 0, stream>>>(smax, zPzPart, out);
}